// Round 1
// baseline (372.961 us; speedup 1.0000x reference)
//
#include <hip/hip_runtime.h>
#include <math.h>

#define N_ 4096
#define F_ 128
#define D_ 64
#define KH_ 3
#define ZS_ 16             // K-split for agemm (grid 16*3*16 = 768 = 3 blocks/CU)
#define KC_ (N_ / ZS_)     // 256 columns per z-slice
#define BM_ 256            // agemm row-tile

// workspace layout (float offsets)
#define OFF_E      0                          // N*D           = 262144
#define OFF_XW     (N_*D_)                    // KH*N*D        = 786432
#define OFF_SE     (OFF_XW + KH_*N_*D_)       // D             = 64
#define OFF_T      (OFF_SE + D_)              // KH*D*D        = 12288
#define OFF_DVEC   (OFF_T + KH_*D_*D_)        // KH*N          = 12288
#define OFF_YT     (OFF_DVEC + KH_*N_)        // KH*D*N bf16   = 393216 floats
#define OFF_AYP    (OFF_YT + KH_*D_*N_/2)     // ZS*KH*N*D     = 12582912
#define OFF_ABF    (OFF_AYP + ZS_*KH_*N_*D_)  // KH*N*N bf16   = 25165824 floats
// total = OFF_ABF + KH_*N_*N_/2 = 39.2M floats ~= 157 MB (ws is 768 MB)

typedef __attribute__((ext_vector_type(8))) short bf16x8;
typedef __attribute__((ext_vector_type(4))) float f32x4;

static __device__ __forceinline__ unsigned short f2bf(float f) {
  union { float f; unsigned u; } v; v.f = f;
  unsigned r = (v.u + 0x7fffu + ((v.u >> 16) & 1u)) >> 16;
  return (unsigned short)r;
}

static __device__ __forceinline__ void gload_lds16(const unsigned short* g,
                                                   unsigned short* l) {
  __builtin_amdgcn_global_load_lds(
      (__attribute__((address_space(1))) unsigned int*)g,
      (__attribute__((address_space(3))) unsigned int*)l, 16, 0, 0);
}

// ------- proj: E = X@W_emb, XW[k] = X@W_hops[k]; fused colsum(E) -> S ------
__global__ __launch_bounds__(256) void proj_kernel(
    const float* __restrict__ X, const float* __restrict__ W_emb,
    const float* __restrict__ W_hops, float* __restrict__ ws)
{
  __shared__ __align__(16) float sXT[32][68];  // [f][i]
  __shared__ __align__(16) float sW[32][68];   // [f][d]
  const int t = threadIdx.x;
  const int m = blockIdx.y;            // 0 -> E, 1..3 -> XW[m-1]
  const int row0 = blockIdx.x * 64;
  const float* W = (m == 0) ? W_emb : (W_hops + (size_t)(m - 1) * F_ * D_);
  float* out = (m == 0) ? (ws + OFF_E) : (ws + OFF_XW + (size_t)(m - 1) * N_ * D_);
  const int tx = t & 15, ty = t >> 4;
  const int d0 = tx * 4, i0 = ty * 4;
  float acc[4][4] = {};
  for (int fc = 0; fc < F_; fc += 32) {
    {
      int i_l = t >> 3;               // 0..31
      int f_l = (t & 7) * 4;          // 0..28
      for (int r = 0; r < 2; ++r) {
        int i = i_l + r * 32;
        float4 v = *(const float4*)(X + (size_t)(row0 + i) * F_ + fc + f_l);
        sXT[f_l + 0][i] = v.x; sXT[f_l + 1][i] = v.y;
        sXT[f_l + 2][i] = v.z; sXT[f_l + 3][i] = v.w;
      }
      int f2 = t >> 4;                // 0..15
      int d  = (t & 15) * 4;
      for (int r = 0; r < 2; ++r) {
        int f = f2 + r * 16;
        *(float4*)&sW[f][d] = *(const float4*)(W + (size_t)(fc + f) * D_ + d);
      }
    }
    __syncthreads();
#pragma unroll 8
    for (int f = 0; f < 32; ++f) {
      float a[4], b[4];
      *(float4*)a = *(const float4*)&sXT[f][i0];
      *(float4*)b = *(const float4*)&sW[f][d0];
      for (int x = 0; x < 4; ++x)
        for (int y = 0; y < 4; ++y)
          acc[x][y] += a[x] * b[y];
    }
    __syncthreads();
  }
  for (int x = 0; x < 4; ++x)
    *(float4*)(out + (size_t)(row0 + i0 + x) * D_ + d0) = *(float4*)acc[x];
  if (m == 0) {
    float p[4];
    for (int y = 0; y < 4; ++y)
      p[y] = acc[0][y] + acc[1][y] + acc[2][y] + acc[3][y];
    *(float4*)&sXT[ty][d0] = *(float4*)p;
    __syncthreads();
    if (ty < 4) {
      int c = ty * 16 + tx;
      float s = 0.f;
#pragma unroll
      for (int r = 0; r < 16; ++r) s += sXT[r][c];
      atomicAdd(ws + OFF_SE + c, s);
    }
  }
}

// -- degconv: dvec[k][i] = (rowsum(A_k)_i + alpha*E_i.S)^-1/2; Abf = bf16(A) --
// Single fp32 pass over A (192 MB); bf16 copy (96 MB) feeds agemm via LLC.
__global__ __launch_bounds__(256) void degconv_kernel(
    const float* __restrict__ A, const float* __restrict__ E,
    const float* __restrict__ S, const float* __restrict__ alpha_p,
    float* __restrict__ dvec, unsigned short* __restrict__ Abf)
{
  int lane = threadIdx.x & 63;
  int wave = threadIdx.x >> 6;
  int row = blockIdx.x * 4 + wave;     // 0..KH*N-1
  int i = row & (N_ - 1);
  const float4* Ar = (const float4*)(A + (size_t)row * N_);
  unsigned short* Br = Abf + (size_t)row * N_;
  float s = 0.f;
#pragma unroll
  for (int it = 0; it < 8; ++it) {
    float4 v0 = Ar[it * 128 + lane * 2 + 0];
    float4 v1 = Ar[it * 128 + lane * 2 + 1];
    s += (v0.x + v0.y) + (v0.z + v0.w) + (v1.x + v1.y) + (v1.z + v1.w);
    union { unsigned short u[8]; uint4 q; } pk;
    pk.u[0] = f2bf(v0.x); pk.u[1] = f2bf(v0.y);
    pk.u[2] = f2bf(v0.z); pk.u[3] = f2bf(v0.w);
    pk.u[4] = f2bf(v1.x); pk.u[5] = f2bf(v1.y);
    pk.u[6] = f2bf(v1.z); pk.u[7] = f2bf(v1.w);
    *(uint4*)(Br + (size_t)it * 512 + lane * 8) = pk.q;
  }
  float alpha = *alpha_p;
  s += alpha * E[(size_t)i * D_ + lane] * S[lane];
#pragma unroll
  for (int off = 32; off > 0; off >>= 1)
    s += __shfl_xor(s, off);
  if (lane == 0) dvec[row] = 1.0f / sqrtf(s);
}

// ------- prep (merged): x<64 -> yprep block; x>=64 -> tmat block ----------
__global__ __launch_bounds__(256) void prep_kernel(float* __restrict__ ws,
                                                   float* __restrict__ T)
{
  const int k = blockIdx.y;
  const float* XWk = ws + OFF_XW + (size_t)k * N_ * D_;
  const float* dk  = ws + OFF_DVEC + (size_t)k * N_;
  int t = threadIdx.x;

  if (blockIdx.x < 64) {
    const int j0 = blockIdx.x * 64;
    unsigned short* Ytk = (unsigned short*)(ws + OFF_YT) + (size_t)k * D_ * N_;
    __shared__ float sT[64][65];         // [n][j]
    {
      int j = t >> 2;
      int c0 = (t & 3) * 16;
      float dv = dk[j0 + j];
      for (int r = 0; r < 4; ++r) {
        float4 v = *(const float4*)(XWk + (size_t)(j0 + j) * D_ + c0 + 4 * r);
        sT[c0 + 4 * r + 0][j] = v.x * dv;
        sT[c0 + 4 * r + 1][j] = v.y * dv;
        sT[c0 + 4 * r + 2][j] = v.z * dv;
        sT[c0 + 4 * r + 3][j] = v.w * dv;
      }
    }
    __syncthreads();
    {
      int n = t >> 2;
      int jq = (t & 3) * 16;
      __align__(16) unsigned short buf[16];
#pragma unroll
      for (int i = 0; i < 16; ++i) buf[i] = f2bf(sT[n][jq + i]);
      uint4* dst = (uint4*)(Ytk + (size_t)n * N_ + j0 + jq);
      dst[0] = *(uint4*)&buf[0];
      dst[1] = *(uint4*)&buf[8];
    }
  } else {
    const float* E = ws + OFF_E;
    __shared__ __align__(16) float sE[32][68];
    __shared__ __align__(16) float sY[32][68];
    int tx = t & 15, ty = t >> 4;
    int d0 = tx * 4, c0 = ty * 4;
    float acc[4][4] = {};
    int base0 = (blockIdx.x - 64) * 128;
    for (int sub = 0; sub < 4; ++sub) {
      int base = base0 + sub * 32;
      {
        int i_l = t >> 3;
        int c   = (t & 7) * 4;
        float dv = dk[base + i_l];
        for (int r = 0; r < 2; ++r) {
          int col = c + r * 32;
          *(float4*)&sE[i_l][col] = *(const float4*)(E + (size_t)(base + i_l) * D_ + col);
          float4 y = *(const float4*)(XWk + (size_t)(base + i_l) * D_ + col);
          y.x *= dv; y.y *= dv; y.z *= dv; y.w *= dv;
          *(float4*)&sY[i_l][col] = y;
        }
      }
      __syncthreads();
#pragma unroll 8
      for (int i = 0; i < 32; ++i) {
        float c4[4], y4[4];
        *(float4*)c4 = *(const float4*)&sE[i][c0];
        *(float4*)y4 = *(const float4*)&sY[i][d0];
        for (int a = 0; a < 4; ++a)
          for (int b = 0; b < 4; ++b)
            acc[a][b] += c4[a] * y4[b];
      }
      __syncthreads();
    }
    float* Tk = T + (size_t)k * D_ * D_;
    for (int a = 0; a < 4; ++a)
      for (int b = 0; b < 4; ++b)
        atomicAdd(&Tk[(c0 + a) * D_ + d0 + b], acc[a][b]);
  }
}

// ---- main GEMM (MFMA bf16, DMA-staged): AYp[z][k] = Abf_k[:,kz] @ Y_k[kz] ----
// BM=256, each wave owns a 64x64 output tile (ds_read:MFMA ratio 0.5).
// LDS linear (global_load_lds requirement); bank spread via chunk ^= row&7
// applied on BOTH the global source address and the ds_read address.
__global__ __launch_bounds__(256, 3) void agemm_kernel(
    const float* __restrict__ ws, float* __restrict__ AYp)
{
  const int k = blockIdx.y;
  const int row0 = blockIdx.x * BM_;
  const int kz0 = blockIdx.z * KC_;
  const unsigned short* Ak = (const unsigned short*)(ws + OFF_ABF) + ((size_t)k << 24);
  const unsigned short* Ytk = (const unsigned short*)(ws + OFF_YT) + (size_t)k * D_ * N_;

  __shared__ __align__(16) unsigned short sA[BM_ * 64];  // 32 KB, linear
  __shared__ __align__(16) unsigned short sY[64 * 64];   // 8 KB, linear

  const int t = threadIdx.x;
  const int lane = t & 63;
  const int w = t >> 6;                // wave 0..3 -> rows w*64..w*64+63
  const int m = lane & 15;
  const int q = lane >> 4;
  const int sr = t >> 3;               // staging row within 32-row group
  const int sc = t & 7;                // staging chunk 0..7 (16B units)

  f32x4 acc[4][4];
#pragma unroll
  for (int a = 0; a < 4; ++a)
#pragma unroll
    for (int b = 0; b < 4; ++b) acc[a][b] = (f32x4){0.f, 0.f, 0.f, 0.f};

  for (int kt = 0; kt < KC_; kt += 64) {
    // stage A: 256 rows x 64 k bf16 = 32 KB, 8 DMA issues
#pragma unroll
    for (int j = 0; j < 8; ++j) {
      int r = j * 32 + sr;
      gload_lds16(Ak + (size_t)(row0 + r) * N_ + (kz0 + kt) + ((sc ^ (r & 7)) << 3),
                  &sA[j * 2048 + t * 8]);
    }
    // stage Y: 64 n x 64 k bf16 = 8 KB, 2 DMA issues
#pragma unroll
    for (int j = 0; j < 2; ++j) {
      int r = j * 32 + sr;
      gload_lds16(Ytk + (size_t)r * N_ + (kz0 + kt) + ((sc ^ (r & 7)) << 3),
                  &sY[j * 2048 + t * 8]);
    }
    __syncthreads();   // compiler drains vmcnt(0) before s_barrier
#pragma unroll
    for (int s = 0; s < 2; ++s) {
      bf16x8 av[4], bv[4];
#pragma unroll
      for (int mr = 0; mr < 4; ++mr) {
        int row = w * 64 + mr * 16 + m;
        av[mr] = *(const bf16x8*)&sA[row * 64 + (((s * 4 + q) ^ (row & 7)) << 3)];
      }
#pragma unroll
      for (int nt = 0; nt < 4; ++nt) {
        int n = nt * 16 + m;
        bv[nt] = *(const bf16x8*)&sY[n * 64 + (((s * 4 + q) ^ (n & 7)) << 3)];
      }
#pragma unroll
      for (int mr = 0; mr < 4; ++mr)
#pragma unroll
        for (int nt = 0; nt < 4; ++nt)
          acc[mr][nt] = __builtin_amdgcn_mfma_f32_16x16x32_bf16(av[mr], bv[nt],
                                                                acc[mr][nt], 0, 0, 0);
    }
    __syncthreads();
  }
  // C/D layout: col = lane&15, row = q*4 + reg
#pragma unroll
  for (int mr = 0; mr < 4; ++mr) {
    float* outp = AYp + (((size_t)blockIdx.z * KH_ + k) * N_ + row0 + w * 64 + mr * 16) * D_;
#pragma unroll
    for (int nt = 0; nt < 4; ++nt)
#pragma unroll
      for (int r = 0; r < 4; ++r)
        outp[(size_t)(q * 4 + r) * D_ + nt * 16 + m] = acc[mr][nt][r];
  }
}

// ---------------- epilogue: out = relu(sum_k d_i*(AY + alpha*E@T_k)) -------
__global__ __launch_bounds__(256) void epilogue_kernel(
    const float* __restrict__ ws, const float* __restrict__ alpha_p,
    float* __restrict__ out)
{
  int g = blockIdx.x * 256 + threadIdx.x;
  int i = g >> 6, d = g & 63;
  const float* E    = ws + OFF_E;
  const float* T    = ws + OFF_T;
  const float* dvec = ws + OFF_DVEC;
  const float* AYp  = ws + OFF_AYP;
  float alpha = *alpha_p;
  float s = 0.f;
  for (int k = 0; k < KH_; ++k) {
    float ay = 0.f;
#pragma unroll
    for (int jc = 0; jc < ZS_; ++jc)
      ay += AYp[(((size_t)jc * KH_ + k) * N_ + i) * D_ + d];
    float lr = 0.f;
    const float* Tk = T + k * D_ * D_;
#pragma unroll 16
    for (int c = 0; c < D_; ++c)
      lr += E[(size_t)i * D_ + c] * Tk[c * D_ + d];
    s += dvec[k * N_ + i] * (ay + alpha * lr);
  }
  out[g] = fmaxf(s, 0.f);
}

extern "C" void kernel_launch(void* const* d_in, const int* in_sizes, int n_in,
                              void* d_out, int out_size, void* d_ws, size_t ws_size,
                              hipStream_t stream) {
  const float* X      = (const float*)d_in[0];
  const float* A      = (const float*)d_in[1];
  const float* W_emb  = (const float*)d_in[2];
  const float* W_hops = (const float*)d_in[3];
  const float* alpha_p= (const float*)d_in[4];
  float* out = (float*)d_out;
  float* ws  = (float*)d_ws;

  // zero S_E and T (accumulated via atomics) — contiguous region
  hipMemsetAsync(ws + OFF_SE, 0, (D_ + KH_ * D_ * D_) * sizeof(float), stream);

  proj_kernel<<<dim3(N_ / 64, 4), 256, 0, stream>>>(X, W_emb, W_hops, ws);
  degconv_kernel<<<dim3(KH_ * N_ / 4), 256, 0, stream>>>(
      A, ws + OFF_E, ws + OFF_SE, alpha_p, ws + OFF_DVEC,
      (unsigned short*)(ws + OFF_ABF));
  prep_kernel<<<dim3(96, KH_), 256, 0, stream>>>(ws, ws + OFF_T);
  agemm_kernel<<<dim3(N_ / BM_, KH_, ZS_), 256, 0, stream>>>(ws, ws + OFF_AYP);
  epilogue_kernel<<<dim3(N_ * D_ / 256), 256, 0, stream>>>(ws, alpha_p, out);
}

// Round 2
// 351.034 us; speedup vs baseline: 1.0625x; 1.0625x over previous
//
#include <hip/hip_runtime.h>
#include <math.h>

#define N_ 4096
#define F_ 128
#define D_ 64
#define KH_ 3
#define ZS_ 16             // K-split for agemm (grid 16*3*16 = 768 = 3 blocks/CU)
#define KC_ (N_ / ZS_)     // 256 columns per z-slice
#define BM_ 256            // agemm row-tile

// workspace layout (float offsets)
#define OFF_E      0                          // N*D           = 262144
#define OFF_XW     (N_*D_)                    // KH*N*D        = 786432
#define OFF_SE     (OFF_XW + KH_*N_*D_)       // D             = 64
#define OFF_T      (OFF_SE + D_)              // KH*D*D        = 12288
#define OFF_RS     (OFF_T + KH_*D_*D_)        // KH*N raw rowsums
#define OFF_DVEC   (OFF_RS + KH_*N_)          // KH*N
#define OFF_YT     (OFF_DVEC + KH_*N_)        // KH*D*N bf16   = 393216 floats
#define OFF_AYP    (OFF_YT + KH_*D_*N_/2)     // ZS*KH*N*D     = 12582912
#define OFF_ABF    (OFF_AYP + ZS_*KH_*N_*D_)  // KH*N*N bf16   = 25165824 floats

typedef __attribute__((ext_vector_type(8))) short bf16x8;
typedef __attribute__((ext_vector_type(4))) float f32x4;

static __device__ __forceinline__ unsigned short f2bf(float f) {
  union { float f; unsigned u; } v; v.f = f;
  unsigned r = (v.u + 0x7fffu + ((v.u >> 16) & 1u)) >> 16;
  return (unsigned short)r;
}

static __device__ __forceinline__ void gload_lds16(const unsigned short* g,
                                                   unsigned short* l) {
  __builtin_amdgcn_global_load_lds(
      (__attribute__((address_space(1))) unsigned int*)g,
      (__attribute__((address_space(3))) unsigned int*)l, 16, 0, 0);
}

// -- degconv (FIRST kernel): rs[k][i] = rowsum(A_k)_i; Abf = bf16(A).
//    A fp32 loads are NONTEMPORAL (dead after this pass) so the 96 MB Abf
//    stays LLC-resident for agemm. Block 0 also zeros SE+T (atomics targets).
__global__ __launch_bounds__(256) void degconv_kernel(
    const float* __restrict__ A, float* __restrict__ ws)
{
  if (blockIdx.x == 0) {
    for (int i = threadIdx.x; i < D_ + KH_ * D_ * D_; i += 256)
      ws[OFF_SE + i] = 0.f;
  }
  int lane = threadIdx.x & 63;
  int wave = threadIdx.x >> 6;
  int row = blockIdx.x * 4 + wave;     // 0..KH*N-1
  const f32x4* Ar = (const f32x4*)(A + (size_t)row * N_);
  unsigned short* Br = (unsigned short*)(ws + OFF_ABF) + (size_t)row * N_;
  float s = 0.f;
#pragma unroll
  for (int it = 0; it < 8; ++it) {
    f32x4 v0 = __builtin_nontemporal_load(Ar + it * 128 + lane * 2 + 0);
    f32x4 v1 = __builtin_nontemporal_load(Ar + it * 128 + lane * 2 + 1);
    s += (v0[0] + v0[1]) + (v0[2] + v0[3]) + (v1[0] + v1[1]) + (v1[2] + v1[3]);
    union { unsigned short u[8]; uint4 q; } pk;
    pk.u[0] = f2bf(v0[0]); pk.u[1] = f2bf(v0[1]);
    pk.u[2] = f2bf(v0[2]); pk.u[3] = f2bf(v0[3]);
    pk.u[4] = f2bf(v1[0]); pk.u[5] = f2bf(v1[1]);
    pk.u[6] = f2bf(v1[2]); pk.u[7] = f2bf(v1[3]);
    *(uint4*)(Br + (size_t)it * 512 + lane * 8) = pk.q;
  }
#pragma unroll
  for (int off = 32; off > 0; off >>= 1)
    s += __shfl_xor(s, off);
  if (lane == 0) ws[OFF_RS + row] = s;
}

// ------- proj: E = X@W_emb, XW[k] = X@W_hops[k]; fused colsum(E) -> S ------
__global__ __launch_bounds__(256) void proj_kernel(
    const float* __restrict__ X, const float* __restrict__ W_emb,
    const float* __restrict__ W_hops, float* __restrict__ ws)
{
  __shared__ __align__(16) float sXT[32][68];  // [f][i]
  __shared__ __align__(16) float sW[32][68];   // [f][d]
  const int t = threadIdx.x;
  const int m = blockIdx.y;            // 0 -> E, 1..3 -> XW[m-1]
  const int row0 = blockIdx.x * 64;
  const float* W = (m == 0) ? W_emb : (W_hops + (size_t)(m - 1) * F_ * D_);
  float* out = (m == 0) ? (ws + OFF_E) : (ws + OFF_XW + (size_t)(m - 1) * N_ * D_);
  const int tx = t & 15, ty = t >> 4;
  const int d0 = tx * 4, i0 = ty * 4;
  float acc[4][4] = {};
  for (int fc = 0; fc < F_; fc += 32) {
    {
      int i_l = t >> 3;               // 0..31
      int f_l = (t & 7) * 4;          // 0..28
      for (int r = 0; r < 2; ++r) {
        int i = i_l + r * 32;
        float4 v = *(const float4*)(X + (size_t)(row0 + i) * F_ + fc + f_l);
        sXT[f_l + 0][i] = v.x; sXT[f_l + 1][i] = v.y;
        sXT[f_l + 2][i] = v.z; sXT[f_l + 3][i] = v.w;
      }
      int f2 = t >> 4;                // 0..15
      int d  = (t & 15) * 4;
      for (int r = 0; r < 2; ++r) {
        int f = f2 + r * 16;
        *(float4*)&sW[f][d] = *(const float4*)(W + (size_t)(fc + f) * D_ + d);
      }
    }
    __syncthreads();
#pragma unroll 8
    for (int f = 0; f < 32; ++f) {
      float a[4], b[4];
      *(float4*)a = *(const float4*)&sXT[f][i0];
      *(float4*)b = *(const float4*)&sW[f][d0];
      for (int x = 0; x < 4; ++x)
        for (int y = 0; y < 4; ++y)
          acc[x][y] += a[x] * b[y];
    }
    __syncthreads();
  }
  for (int x = 0; x < 4; ++x)
    *(float4*)(out + (size_t)(row0 + i0 + x) * D_ + d0) = *(float4*)acc[x];
  if (m == 0) {
    float p[4];
    for (int y = 0; y < 4; ++y)
      p[y] = acc[0][y] + acc[1][y] + acc[2][y] + acc[3][y];
    *(float4*)&sXT[ty][d0] = *(float4*)p;
    __syncthreads();
    if (ty < 4) {
      int c = ty * 16 + tx;
      float s = 0.f;
#pragma unroll
      for (int r = 0; r < 16; ++r) s += sXT[r][c];
      atomicAdd(ws + OFF_SE + c, s);
    }
  }
}

// ------- prep (merged): x<64 -> yprep; x>=64 -> tmat.  Computes dvec inline:
//         d = rsqrt(rs + alpha * E_row . S); yprep also stores dvec for epilogue.
__global__ __launch_bounds__(256) void prep_kernel(float* __restrict__ ws,
                                                   const float* __restrict__ alpha_p)
{
  const int k = blockIdx.y;
  const float* XWk = ws + OFF_XW + (size_t)k * N_ * D_;
  const float* E   = ws + OFF_E;
  const float* Sv  = ws + OFF_SE;
  const float* rs  = ws + OFF_RS + (size_t)k * N_;
  const float alpha = *alpha_p;
  int t = threadIdx.x;

  if (blockIdx.x < 64) {
    // ---------------- yprep role ----------------
    const int j0 = blockIdx.x * 64;
    unsigned short* Ytk = (unsigned short*)(ws + OFF_YT) + (size_t)k * D_ * N_;
    __shared__ float sS[64];
    __shared__ float d_l[64];
    __shared__ __align__(16) float sEy[64][65];
    __shared__ float sT[64][65];         // [n][j]
    if (t < 64) sS[t] = Sv[t];
    {
      int j = t >> 2;
      int c0 = (t & 3) * 16;
      for (int r = 0; r < 4; ++r)
        *(float4*)&sEy[j][c0 + 4 * r] = *(const float4*)(E + (size_t)(j0 + j) * D_ + c0 + 4 * r);
    }
    __syncthreads();
    if (t < 64) {
      float dot = 0.f;
#pragma unroll 16
      for (int c = 0; c < 64; ++c) dot += sEy[t][c] * sS[c];
      float dv = 1.0f / sqrtf(rs[j0 + t] + alpha * dot);
      d_l[t] = dv;
      ws[OFF_DVEC + (size_t)k * N_ + j0 + t] = dv;
    }
    __syncthreads();
    {
      int j = t >> 2;
      int c0 = (t & 3) * 16;
      float dv = d_l[j];
      for (int r = 0; r < 4; ++r) {
        float4 v = *(const float4*)(XWk + (size_t)(j0 + j) * D_ + c0 + 4 * r);
        sT[c0 + 4 * r + 0][j] = v.x * dv;
        sT[c0 + 4 * r + 1][j] = v.y * dv;
        sT[c0 + 4 * r + 2][j] = v.z * dv;
        sT[c0 + 4 * r + 3][j] = v.w * dv;
      }
    }
    __syncthreads();
    {
      int n = t >> 2;
      int jq = (t & 3) * 16;
      __align__(16) unsigned short buf[16];
#pragma unroll
      for (int i = 0; i < 16; ++i) buf[i] = f2bf(sT[n][jq + i]);
      uint4* dst = (uint4*)(Ytk + (size_t)n * N_ + j0 + jq);
      dst[0] = *(uint4*)&buf[0];
      dst[1] = *(uint4*)&buf[8];
    }
  } else {
    // ---------------- tmat role: T_k += E^T @ (d ⊙ XW_k) ----------------
    __shared__ float sS2[64];
    __shared__ float dl2[128];
    __shared__ __align__(16) float sE[32][68];
    __shared__ __align__(16) float sY[32][68];
    int base0 = (blockIdx.x - 64) * 128;
    if (t < 64) sS2[t] = Sv[t];
    __syncthreads();
    if (t < 128) {
      int jr = base0 + t;
      float dot = 0.f;
#pragma unroll 16
      for (int c = 0; c < 64; ++c) dot += E[(size_t)jr * D_ + c] * sS2[c];
      dl2[t] = 1.0f / sqrtf(rs[jr] + alpha * dot);
    }
    __syncthreads();
    int tx = t & 15, ty = t >> 4;
    int d0 = tx * 4, c0 = ty * 4;
    float acc[4][4] = {};
    for (int sub = 0; sub < 4; ++sub) {
      int base = base0 + sub * 32;
      {
        int i_l = t >> 3;
        int c   = (t & 7) * 4;
        float dv = dl2[sub * 32 + i_l];
        for (int r = 0; r < 2; ++r) {
          int col = c + r * 32;
          *(float4*)&sE[i_l][col] = *(const float4*)(E + (size_t)(base + i_l) * D_ + col);
          float4 y = *(const float4*)(XWk + (size_t)(base + i_l) * D_ + col);
          y.x *= dv; y.y *= dv; y.z *= dv; y.w *= dv;
          *(float4*)&sY[i_l][col] = y;
        }
      }
      __syncthreads();
#pragma unroll 8
      for (int i = 0; i < 32; ++i) {
        float c4[4], y4[4];
        *(float4*)c4 = *(const float4*)&sE[i][c0];
        *(float4*)y4 = *(const float4*)&sY[i][d0];
        for (int a = 0; a < 4; ++a)
          for (int b = 0; b < 4; ++b)
            acc[a][b] += c4[a] * y4[b];
      }
      __syncthreads();
    }
    float* Tk = ws + OFF_T + (size_t)k * D_ * D_;
    for (int a = 0; a < 4; ++a)
      for (int b = 0; b < 4; ++b)
        atomicAdd(&Tk[(c0 + a) * D_ + d0 + b], acc[a][b]);
  }
}

// ---- main GEMM (MFMA bf16, DMA-staged): AYp[z][k] = Abf_k[:,kz] @ Y_k[kz] ----
__global__ __launch_bounds__(256, 3) void agemm_kernel(
    const float* __restrict__ ws, float* __restrict__ AYp)
{
  const int k = blockIdx.y;
  const int row0 = blockIdx.x * BM_;
  const int kz0 = blockIdx.z * KC_;
  const unsigned short* Ak = (const unsigned short*)(ws + OFF_ABF) + ((size_t)k << 24);
  const unsigned short* Ytk = (const unsigned short*)(ws + OFF_YT) + (size_t)k * D_ * N_;

  __shared__ __align__(16) unsigned short sA[BM_ * 64];  // 32 KB, linear
  __shared__ __align__(16) unsigned short sY[64 * 64];   // 8 KB, linear

  const int t = threadIdx.x;
  const int lane = t & 63;
  const int w = t >> 6;                // wave 0..3 -> rows w*64..w*64+63
  const int m = lane & 15;
  const int q = lane >> 4;
  const int sr = t >> 3;               // staging row within 32-row group
  const int sc = t & 7;                // staging chunk 0..7 (16B units)

  f32x4 acc[4][4];
#pragma unroll
  for (int a = 0; a < 4; ++a)
#pragma unroll
    for (int b = 0; b < 4; ++b) acc[a][b] = (f32x4){0.f, 0.f, 0.f, 0.f};

  for (int kt = 0; kt < KC_; kt += 64) {
#pragma unroll
    for (int j = 0; j < 8; ++j) {
      int r = j * 32 + sr;
      gload_lds16(Ak + (size_t)(row0 + r) * N_ + (kz0 + kt) + ((sc ^ (r & 7)) << 3),
                  &sA[j * 2048 + t * 8]);
    }
#pragma unroll
    for (int j = 0; j < 2; ++j) {
      int r = j * 32 + sr;
      gload_lds16(Ytk + (size_t)r * N_ + (kz0 + kt) + ((sc ^ (r & 7)) << 3),
                  &sY[j * 2048 + t * 8]);
    }
    __syncthreads();
#pragma unroll
    for (int s = 0; s < 2; ++s) {
      bf16x8 av[4], bv[4];
#pragma unroll
      for (int mr = 0; mr < 4; ++mr) {
        int row = w * 64 + mr * 16 + m;
        av[mr] = *(const bf16x8*)&sA[row * 64 + (((s * 4 + q) ^ (row & 7)) << 3)];
      }
#pragma unroll
      for (int nt = 0; nt < 4; ++nt) {
        int n = nt * 16 + m;
        bv[nt] = *(const bf16x8*)&sY[n * 64 + (((s * 4 + q) ^ (n & 7)) << 3)];
      }
#pragma unroll
      for (int mr = 0; mr < 4; ++mr)
#pragma unroll
        for (int nt = 0; nt < 4; ++nt)
          acc[mr][nt] = __builtin_amdgcn_mfma_f32_16x16x32_bf16(av[mr], bv[nt],
                                                                acc[mr][nt], 0, 0, 0);
    }
    __syncthreads();
  }
  // C/D layout: col = lane&15, row = q*4 + reg
#pragma unroll
  for (int mr = 0; mr < 4; ++mr) {
    float* outp = AYp + (((size_t)blockIdx.z * KH_ + k) * N_ + row0 + w * 64 + mr * 16) * D_;
#pragma unroll
    for (int nt = 0; nt < 4; ++nt)
#pragma unroll
      for (int r = 0; r < 4; ++r)
        outp[(size_t)(q * 4 + r) * D_ + nt * 16 + m] = acc[mr][nt][r];
  }
}

// ---------------- epilogue: out = relu(sum_k d_i*(AY + alpha*E@T_k)) -------
__global__ __launch_bounds__(256) void epilogue_kernel(
    const float* __restrict__ ws, const float* __restrict__ alpha_p,
    float* __restrict__ out)
{
  int g = blockIdx.x * 256 + threadIdx.x;
  int i = g >> 6, d = g & 63;
  const float* E    = ws + OFF_E;
  const float* T    = ws + OFF_T;
  const float* dvec = ws + OFF_DVEC;
  const float* AYp  = ws + OFF_AYP;
  float alpha = *alpha_p;
  float s = 0.f;
  for (int k = 0; k < KH_; ++k) {
    float ay = 0.f;
#pragma unroll
    for (int jc = 0; jc < ZS_; ++jc)
      ay += AYp[(((size_t)jc * KH_ + k) * N_ + i) * D_ + d];
    float lr = 0.f;
    const float* Tk = T + k * D_ * D_;
#pragma unroll 16
    for (int c = 0; c < D_; ++c)
      lr += E[(size_t)i * D_ + c] * Tk[c * D_ + d];
    s += dvec[k * N_ + i] * (ay + alpha * lr);
  }
  out[g] = fmaxf(s, 0.f);
}

extern "C" void kernel_launch(void* const* d_in, const int* in_sizes, int n_in,
                              void* d_out, int out_size, void* d_ws, size_t ws_size,
                              hipStream_t stream) {
  const float* X      = (const float*)d_in[0];
  const float* A      = (const float*)d_in[1];
  const float* W_emb  = (const float*)d_in[2];
  const float* W_hops = (const float*)d_in[3];
  const float* alpha_p= (const float*)d_in[4];
  float* out = (float*)d_out;
  float* ws  = (float*)d_ws;

  degconv_kernel<<<dim3(KH_ * N_ / 4), 256, 0, stream>>>(A, ws);
  proj_kernel<<<dim3(N_ / 64, 4), 256, 0, stream>>>(X, W_emb, W_hops, ws);
  prep_kernel<<<dim3(96, KH_), 256, 0, stream>>>(ws, alpha_p);
  agemm_kernel<<<dim3(N_ / BM_, KH_, ZS_), 256, 0, stream>>>(ws, ws + OFF_AYP);
  epilogue_kernel<<<dim3(N_ * D_ / 256), 256, 0, stream>>>(ws, alpha_p, out);
}